// Round 11
// baseline (222.802 us; speedup 1.0000x reference)
//
#include <hip/hip_runtime.h>

// Problem constants: B=16, MAX_LEN=100, LOC_MAX=20000, EMB=256, D_DELTA=2
#define NB 16
#define MLEN 100
#define EMBD 256
#define LMAX 20000
#define LTILE 128           // l's per block (M dim)
#define NLT 157             // ceil(20000/128)
#define NKC 4               // K chunks of 32 m's (100 padded to 128)
#define FSTRIDE 520         // u16 per lt sub-tile: 64 lanes * 8 + 8 pad (1040 B, 16B-aligned)
#define PREP_TASKS (NB * NKC * 16 * 64)   // 65536: (b,kc,etg,lane)

typedef __attribute__((ext_vector_type(4))) float f32x4;
typedef __attribute__((ext_vector_type(8))) short bf16x8;

__device__ __forceinline__ unsigned short f2bf(float x) {
    union { float f; unsigned u; } a; a.f = x;
    unsigned r = a.u + 0x7FFFu + ((a.u >> 16) & 1u);
    return (unsigned short)(r >> 16);
}
__device__ __forceinline__ float bf2f(unsigned short h) {
    union { unsigned u; float f; } a; a.u = ((unsigned)h) << 16;
    return a.f;
}

// ---------------- Kernel 1: pack vwA = vw[m]*attn[b][m][e] into MFMA B-fragments (hi/lo) ----------------
// frag f = (b*NKC+kc)*16 + etg ; lane: e = etg*16 + (lane&15), k = (lane>>4)*8 + j, m = kc*32 + k
__global__ __launch_bounds__(256)
void prep2_kernel(const float* __restrict__ attn, const float* __restrict__ vw,
                  unsigned short* __restrict__ Bhi, unsigned short* __restrict__ Blo) {
    const int gid  = blockIdx.x * 256 + threadIdx.x;   // < 65536
    const int lane = gid & 63;
    const int f    = gid >> 6;
    const int etg  = f & 15;
    const int kcb  = f >> 4;
    const int kc   = kcb & 3;
    const int b    = kcb >> 2;
    const int e    = etg * 16 + (lane & 15);
    const int m0   = kc * 32 + (lane >> 4) * 8;
    unsigned h[8], l[8];
    #pragma unroll
    for (int j = 0; j < 8; ++j) {
        const int m = m0 + j;
        float x = 0.f;
        if (m < MLEN) x = vw[m] * attn[((size_t)b * MLEN + m) * EMBD + e];
        const unsigned short hh = f2bf(x);
        h[j] = hh;
        l[j] = f2bf(x - bf2f(hh));
    }
    uint4 hi = make_uint4(h[0]|(h[1]<<16), h[2]|(h[3]<<16), h[4]|(h[5]<<16), h[6]|(h[7]<<16));
    uint4 lo = make_uint4(l[0]|(l[1]<<16), l[2]|(l[3]<<16), l[4]|(l[5]<<16), l[6]|(l[7]<<16));
    reinterpret_cast<uint4*>(Bhi)[gid] = hi;
    reinterpret_cast<uint4*>(Blo)[gid] = lo;
}

// ---------------- Kernel 2: GEMM G[l,e] = sum_m ds[m,l]*vwA[m,e]; epilogue dot with E ----------------
// Block: (b, 128 l's), 4 waves; wave w owns e-range [w*64, +64). K = 100 m's in 4 chunks of 32.
// ds chunk: global f32x4 (issued one iteration EARLY) -> pair-sum -> hi/lo bf16 -> LDS frag order.
// Loop uses RAW s_barrier + lgkmcnt-only waits: the prefetched chunk is never drained by a barrier.
__global__ __launch_bounds__(256, 3)
void main_kernel(const unsigned short* __restrict__ Bhi, const unsigned short* __restrict__ Blo,
                 const float* __restrict__ sdelta, const float* __restrict__ embt,
                 float* __restrict__ out) {
    __shared__ __align__(16) unsigned short AhL[2][8 * FSTRIDE];  // 2 x 8320 B
    __shared__ __align__(16) unsigned short AlL[2][8 * FSTRIDE];  // 2 x 8320 B
    __shared__ float red[512];                                    // 2048 B  (total 35328 B)

    const int b    = blockIdx.x;
    const int lt0  = blockIdx.y;
    const int l0   = lt0 * LTILE;
    const int w    = threadIdx.x >> 6;
    const int lane = threadIdx.x & 63;
    const int llo  = lane & 15;
    const int lhi  = lane >> 4;

    f32x4 acc[8][4];
    #pragma unroll
    for (int lt = 0; lt < 8; ++lt)
        #pragma unroll
        for (int et = 0; et < 4; ++et)
            acc[lt][et] = (f32x4){0.f, 0.f, 0.f, 0.f};

    // per-lane global source: 2 consecutive l's (one f32x4 = 2 pairs), clamped for edge tile
    const int lcl = min(l0 + 2 * lane, LMAX - 2);

    f32x4 vA[2][8];
    // issue the 8 ds row-loads for chunk kc (wave w covers rows r32 = jj*4+w)
    auto issueA = [&](int kc) {
        const int q = kc & 1;
        #pragma unroll
        for (int jj = 0; jj < 8; ++jj) {
            const int m  = kc * 32 + jj * 4 + w;
            const int mc = (m < MLEN) ? m : (MLEN - 1);
            vA[q][jj] = *reinterpret_cast<const f32x4*>(
                            sdelta + ((size_t)(b * MLEN + mc) * LMAX + lcl) * 2);
        }
    };
    // pair-sum + hi/lo split + LDS write in fragment order (auto counted-vmcnt wait on vA[q])
    auto writeA = [&](int kc) {
        const int q = kc & 1;
        const int lt  = lane >> 3;
        const int lo0 = (2 * lane) & 15;
        #pragma unroll
        for (int jj = 0; jj < 8; ++jj) {
            const int r32 = jj * 4 + w;
            const int m   = kc * 32 + r32;
            const float msk = (m < MLEN) ? 1.f : 0.f;
            const f32x4 v = vA[q][jj];
            const float s0 = (v[0] + v[1]) * msk;
            const float s1 = (v[2] + v[3]) * msk;
            const unsigned short h0 = f2bf(s0); const unsigned short L0 = f2bf(s0 - bf2f(h0));
            const unsigned short h1 = f2bf(s1); const unsigned short L1 = f2bf(s1 - bf2f(h1));
            const int kg = r32 >> 3, j = r32 & 7;
            const int i0 = lt * FSTRIDE + (lo0 | (kg << 4)) * 8 + j;
            AhL[q][i0] = h0;  AhL[q][i0 + 8] = h1;
            AlL[q][i0] = L0;  AlL[q][i0 + 8] = L1;
        }
    };

    issueA(0);
    #pragma unroll
    for (int kc = 0; kc < NKC; ++kc) {
        const int q = kc & 1;
        writeA(kc);                      // waits own chunk only (issued one iter early)
        // LDS-visibility barrier WITHOUT vmcnt drain (raw s_barrier, lgkmcnt only):
        asm volatile("s_waitcnt lgkmcnt(0)" ::: "memory");
        __builtin_amdgcn_sched_barrier(0);
        __builtin_amdgcn_s_barrier();
        __builtin_amdgcn_sched_barrier(0);

        // B fragments for this chunk FIRST (their wait must not cover next A-loads)...
        bf16x8 Bh[4], Bl[4];
        #pragma unroll
        for (int et = 0; et < 4; ++et) {
            const size_t bo = (((size_t)(b * NKC + kc) * 16 + (w * 4 + et)) * 64 + lane) * 8;
            Bh[et] = *reinterpret_cast<const bf16x8*>(Bhi + bo);
            Bl[et] = *reinterpret_cast<const bf16x8*>(Blo + bo);
        }
        __builtin_amdgcn_sched_barrier(0);
        // ...then next chunk's A-loads (newest) — they stay in flight across MFMA AND barrier
        if (kc + 1 < NKC) issueA(kc + 1);
        __builtin_amdgcn_sched_barrier(0);

        #pragma unroll
        for (int lt = 0; lt < 8; ++lt) {
            const bf16x8 ah = *reinterpret_cast<const bf16x8*>(&AhL[q][lt * FSTRIDE + lane * 8]);
            const bf16x8 al = *reinterpret_cast<const bf16x8*>(&AlL[q][lt * FSTRIDE + lane * 8]);
            #pragma unroll
            for (int et = 0; et < 4; ++et) {
                acc[lt][et] = __builtin_amdgcn_mfma_f32_16x16x32_bf16(ah, Bh[et], acc[lt][et], 0, 0, 0);
                acc[lt][et] = __builtin_amdgcn_mfma_f32_16x16x32_bf16(ah, Bl[et], acc[lt][et], 0, 0, 0);
                acc[lt][et] = __builtin_amdgcn_mfma_f32_16x16x32_bf16(al, Bh[et], acc[lt][et], 0, 0, 0);
            }
        }
        // protect buf q for reuse at kc+2 (all reads are register-consumed by now; no waitcnt needed)
        __builtin_amdgcn_sched_barrier(0);
        __builtin_amdgcn_s_barrier();
        __builtin_amdgcn_sched_barrier(0);
    }

    // ---------------- epilogue: p[l] = sum_e G[l,e] * E[1+l, e] ----------------
    // C/D layout: col = lane&15 (e), row = (lane>>4)*4 + i (l)  [verified r1-r10]
    float p[8][4];
    #pragma unroll
    for (int lt = 0; lt < 8; ++lt) {
        #pragma unroll
        for (int i = 0; i < 4; ++i) {
            const int l  = l0 + lt * 16 + lhi * 4 + i;
            const int lc = (l < LMAX) ? l : (LMAX - 1);
            const float* Er = embt + (size_t)(1 + lc) * EMBD + w * 64 + llo;
            float s = acc[lt][0][i] * Er[0];
            s += acc[lt][1][i] * Er[16];
            s += acc[lt][2][i] * Er[32];
            s += acc[lt][3][i] * Er[48];
            p[lt][i] = s;
        }
    }
    #pragma unroll
    for (int lt = 0; lt < 8; ++lt)
        #pragma unroll
        for (int i = 0; i < 4; ++i) {
            float x = p[lt][i];
            x += __shfl_xor(x, 1);
            x += __shfl_xor(x, 2);
            x += __shfl_xor(x, 4);
            x += __shfl_xor(x, 8);
            p[lt][i] = x;
        }
    if (llo == 0) {
        #pragma unroll
        for (int lt = 0; lt < 8; ++lt)
            *reinterpret_cast<float4*>(&red[w * 128 + lt * 16 + lhi * 4]) =
                make_float4(p[lt][0], p[lt][1], p[lt][2], p[lt][3]);
    }
    __syncthreads();
    if (threadIdx.x < 128) {
        const int t = threadIdx.x;
        const int l = l0 + t;
        if (l < LMAX) {
            out[(size_t)b * LMAX + l] = red[t] + red[128 + t] + red[256 + t] + red[384 + t];
        }
    }
}

// ---------------- Fallback (ws too small): straightforward f32 compute ----------------
__global__ __launch_bounds__(256)
void fallback_kernel(const float* __restrict__ attn, const float* __restrict__ sdelta,
                     const float* __restrict__ embt, const float* __restrict__ vw,
                     float* __restrict__ out) {
    const int idx = blockIdx.x * 256 + threadIdx.x;
    if (idx >= NB * LMAX) return;
    const int b = idx / LMAX;
    const int l = idx % LMAX;
    float s = 0.f;
    for (int m = 0; m < MLEN; ++m) {
        const float* ar = attn + ((size_t)b * MLEN + m) * EMBD;
        const float* er = embt + (size_t)(l + 1) * EMBD;
        float dot = 0.f;
        for (int e = 0; e < EMBD; ++e) dot += ar[e] * er[e];
        const size_t so = (((size_t)b * MLEN + m) * LMAX + l) * 2;
        s += dot * vw[m] * (sdelta[so] + sdelta[so + 1]);
    }
    out[idx] = s;
}

extern "C" void kernel_launch(void* const* d_in, const int* in_sizes, int n_in,
                              void* d_out, int out_size, void* d_ws, size_t ws_size,
                              hipStream_t stream) {
    const float* attn   = (const float*)d_in[0];  // [16][100][256] f32
    const float* sdelta = (const float*)d_in[1];  // [16][100][20000][2] f32
    // d_in[2] = traj_len — unused by the reference computation
    const float* embt   = (const float*)d_in[3];  // [20001][256] f32
    const float* vw     = (const float*)d_in[4];  // [1][100] f32
    float* out = (float*)d_out;                   // [16][20000] f32

    const size_t fragShorts = (size_t)PREP_TASKS * 8;            // 524288 u16 per array
    const size_t needed     = 2 * fragShorts * sizeof(unsigned short);  // 2 MB

    if (ws_size >= needed) {
        unsigned short* Bhi = (unsigned short*)d_ws;
        unsigned short* Blo = Bhi + fragShorts;
        prep2_kernel<<<PREP_TASKS / 256, 256, 0, stream>>>(attn, vw, Bhi, Blo);
        main_kernel<<<dim3(NB, NLT), 256, 0, stream>>>(Bhi, Blo, sdelta, embt, out);
    } else {
        fallback_kernel<<<(NB * LMAX + 255) / 256, 256, 0, stream>>>(attn, sdelta, embt, vw, out);
    }
}

// Round 12
// 94.175 us; speedup vs baseline: 2.3658x; 2.3658x over previous
//
#include <hip/hip_runtime.h>

// Problem constants: B=16, MAX_LEN=100, LOC_MAX=20000, EMB=256, D_DELTA=2
#define NB 16
#define MLEN 100
#define EMBD 256
#define LMAX 20000
#define LTILE 128           // l's per block (M dim)
#define NLT 157             // ceil(20000/128)
#define NKC 4               // K chunks of 32 m's (100 padded to 128)
#define FSTRIDE 520         // u16 per lt sub-tile: 64 lanes * 8 + 8 pad (1040 B, 16B-aligned)
#define PREP_TASKS (NB * NKC * 16 * 64)   // 65536: (b,kc,etg,lane)

typedef __attribute__((ext_vector_type(4))) float f32x4;
typedef __attribute__((ext_vector_type(8))) short bf16x8;

__device__ __forceinline__ unsigned short f2bf(float x) {
    union { float f; unsigned u; } a; a.f = x;
    unsigned r = a.u + 0x7FFFu + ((a.u >> 16) & 1u);
    return (unsigned short)(r >> 16);
}
__device__ __forceinline__ float bf2f(unsigned short h) {
    union { unsigned u; float f; } a; a.u = ((unsigned)h) << 16;
    return a.f;
}

// ---------------- Kernel 1: pack vwA = vw[m]*attn[b][m][e] into MFMA B-fragments (hi/lo) ----------------
// frag f = (b*NKC+kc)*16 + etg ; lane: e = etg*16 + (lane&15), k = (lane>>4)*8 + j, m = kc*32 + k
__global__ __launch_bounds__(256)
void prep2_kernel(const float* __restrict__ attn, const float* __restrict__ vw,
                  unsigned short* __restrict__ Bhi, unsigned short* __restrict__ Blo) {
    const int gid  = blockIdx.x * 256 + threadIdx.x;   // < 65536
    const int lane = gid & 63;
    const int f    = gid >> 6;
    const int etg  = f & 15;
    const int kcb  = f >> 4;
    const int kc   = kcb & 3;
    const int b    = kcb >> 2;
    const int e    = etg * 16 + (lane & 15);
    const int m0   = kc * 32 + (lane >> 4) * 8;
    unsigned h[8], l[8];
    #pragma unroll
    for (int j = 0; j < 8; ++j) {
        const int m = m0 + j;
        float x = 0.f;
        if (m < MLEN) x = vw[m] * attn[((size_t)b * MLEN + m) * EMBD + e];
        const unsigned short hh = f2bf(x);
        h[j] = hh;
        l[j] = f2bf(x - bf2f(hh));
    }
    uint4 hi = make_uint4(h[0]|(h[1]<<16), h[2]|(h[3]<<16), h[4]|(h[5]<<16), h[6]|(h[7]<<16));
    uint4 lo = make_uint4(l[0]|(l[1]<<16), l[2]|(l[3]<<16), l[4]|(l[5]<<16), l[6]|(l[7]<<16));
    reinterpret_cast<uint4*>(Bhi)[gid] = hi;
    reinterpret_cast<uint4*>(Blo)[gid] = lo;
}

// ---------------- Kernel 2: GEMM G[l,e] = sum_m ds[m,l]*vwA[m,e]; epilogue dot with E ----------------
// Block: (b, 128 l's), 4 waves; wave w owns e-range [w*64, +64). K = 100 m's in 4 chunks of 32.
// ds chunk: global f32x4 (issued one iteration EARLY) -> pair-sum -> hi/lo bf16 -> LDS frag order.
// Loop uses RAW s_barrier + lgkmcnt-only waits: the prefetched chunk is never drained by a barrier.
// launch_bounds (256,2): VGPR cap 256 -> acc[8][4] + vA[2][8] fit with NO scratch spill (R11 lesson).
__global__ __launch_bounds__(256, 2)
void main_kernel(const unsigned short* __restrict__ Bhi, const unsigned short* __restrict__ Blo,
                 const float* __restrict__ sdelta, const float* __restrict__ embt,
                 float* __restrict__ out) {
    __shared__ __align__(16) unsigned short AhL[2][8 * FSTRIDE];  // 2 x 8320 B
    __shared__ __align__(16) unsigned short AlL[2][8 * FSTRIDE];  // 2 x 8320 B
    __shared__ float red[512];                                    // 2048 B  (total 35328 B)

    const int b    = blockIdx.x;
    const int lt0  = blockIdx.y;
    const int l0   = lt0 * LTILE;
    const int w    = threadIdx.x >> 6;
    const int lane = threadIdx.x & 63;
    const int llo  = lane & 15;
    const int lhi  = lane >> 4;

    f32x4 acc[8][4];
    #pragma unroll
    for (int lt = 0; lt < 8; ++lt)
        #pragma unroll
        for (int et = 0; et < 4; ++et)
            acc[lt][et] = (f32x4){0.f, 0.f, 0.f, 0.f};

    // per-lane global source: 2 consecutive l's (one f32x4 = 2 pairs), clamped for edge tile
    const int lcl = min(l0 + 2 * lane, LMAX - 2);

    f32x4 vA[2][8];
    // issue the 8 ds row-loads for chunk kc (wave w covers rows r32 = jj*4+w)
    auto issueA = [&](int kc) {
        const int q = kc & 1;
        #pragma unroll
        for (int jj = 0; jj < 8; ++jj) {
            const int m  = kc * 32 + jj * 4 + w;
            const int mc = (m < MLEN) ? m : (MLEN - 1);
            vA[q][jj] = *reinterpret_cast<const f32x4*>(
                            sdelta + ((size_t)(b * MLEN + mc) * LMAX + lcl) * 2);
        }
    };
    // pair-sum + hi/lo split + LDS write in fragment order (auto counted-vmcnt wait on vA[q])
    auto writeA = [&](int kc) {
        const int q = kc & 1;
        const int lt  = lane >> 3;
        const int lo0 = (2 * lane) & 15;
        #pragma unroll
        for (int jj = 0; jj < 8; ++jj) {
            const int r32 = jj * 4 + w;
            const int m   = kc * 32 + r32;
            const float msk = (m < MLEN) ? 1.f : 0.f;
            const f32x4 v = vA[q][jj];
            const float s0 = (v[0] + v[1]) * msk;
            const float s1 = (v[2] + v[3]) * msk;
            const unsigned short h0 = f2bf(s0); const unsigned short L0 = f2bf(s0 - bf2f(h0));
            const unsigned short h1 = f2bf(s1); const unsigned short L1 = f2bf(s1 - bf2f(h1));
            const int kg = r32 >> 3, j = r32 & 7;
            const int i0 = lt * FSTRIDE + (lo0 | (kg << 4)) * 8 + j;
            AhL[q][i0] = h0;  AhL[q][i0 + 8] = h1;
            AlL[q][i0] = L0;  AlL[q][i0 + 8] = L1;
        }
    };

    issueA(0);
    #pragma unroll
    for (int kc = 0; kc < NKC; ++kc) {
        const int q = kc & 1;
        writeA(kc);                      // waits own chunk only (issued one iter early)
        // LDS-visibility barrier WITHOUT vmcnt drain (raw s_barrier, lgkmcnt only):
        asm volatile("s_waitcnt lgkmcnt(0)" ::: "memory");
        __builtin_amdgcn_sched_barrier(0);
        __builtin_amdgcn_s_barrier();
        __builtin_amdgcn_sched_barrier(0);

        // B fragments for this chunk FIRST (their wait must not cover next A-loads)...
        bf16x8 Bh[4], Bl[4];
        #pragma unroll
        for (int et = 0; et < 4; ++et) {
            const size_t bo = (((size_t)(b * NKC + kc) * 16 + (w * 4 + et)) * 64 + lane) * 8;
            Bh[et] = *reinterpret_cast<const bf16x8*>(Bhi + bo);
            Bl[et] = *reinterpret_cast<const bf16x8*>(Blo + bo);
        }
        __builtin_amdgcn_sched_barrier(0);
        // ...then next chunk's A-loads (newest) — they stay in flight across MFMA AND barrier
        if (kc + 1 < NKC) issueA(kc + 1);
        __builtin_amdgcn_sched_barrier(0);

        #pragma unroll
        for (int lt = 0; lt < 8; ++lt) {
            const bf16x8 ah = *reinterpret_cast<const bf16x8*>(&AhL[q][lt * FSTRIDE + lane * 8]);
            const bf16x8 al = *reinterpret_cast<const bf16x8*>(&AlL[q][lt * FSTRIDE + lane * 8]);
            #pragma unroll
            for (int et = 0; et < 4; ++et) {
                acc[lt][et] = __builtin_amdgcn_mfma_f32_16x16x32_bf16(ah, Bh[et], acc[lt][et], 0, 0, 0);
                acc[lt][et] = __builtin_amdgcn_mfma_f32_16x16x32_bf16(ah, Bl[et], acc[lt][et], 0, 0, 0);
                acc[lt][et] = __builtin_amdgcn_mfma_f32_16x16x32_bf16(al, Bh[et], acc[lt][et], 0, 0, 0);
            }
        }
        // protect buf q for reuse at kc+2 (reads consumed by MFMAs before this barrier)
        __builtin_amdgcn_sched_barrier(0);
        __builtin_amdgcn_s_barrier();
        __builtin_amdgcn_sched_barrier(0);
    }

    // ---------------- epilogue: p[l] = sum_e G[l,e] * E[1+l, e] ----------------
    // C/D layout: col = lane&15 (e), row = (lane>>4)*4 + i (l)  [verified r1-r11]
    float p[8][4];
    #pragma unroll
    for (int lt = 0; lt < 8; ++lt) {
        #pragma unroll
        for (int i = 0; i < 4; ++i) {
            const int l  = l0 + lt * 16 + lhi * 4 + i;
            const int lc = (l < LMAX) ? l : (LMAX - 1);
            const float* Er = embt + (size_t)(1 + lc) * EMBD + w * 64 + llo;
            float s = acc[lt][0][i] * Er[0];
            s += acc[lt][1][i] * Er[16];
            s += acc[lt][2][i] * Er[32];
            s += acc[lt][3][i] * Er[48];
            p[lt][i] = s;
        }
    }
    #pragma unroll
    for (int lt = 0; lt < 8; ++lt)
        #pragma unroll
        for (int i = 0; i < 4; ++i) {
            float x = p[lt][i];
            x += __shfl_xor(x, 1);
            x += __shfl_xor(x, 2);
            x += __shfl_xor(x, 4);
            x += __shfl_xor(x, 8);
            p[lt][i] = x;
        }
    if (llo == 0) {
        #pragma unroll
        for (int lt = 0; lt < 8; ++lt)
            *reinterpret_cast<float4*>(&red[w * 128 + lt * 16 + lhi * 4]) =
                make_float4(p[lt][0], p[lt][1], p[lt][2], p[lt][3]);
    }
    __syncthreads();
    if (threadIdx.x < 128) {
        const int t = threadIdx.x;
        const int l = l0 + t;
        if (l < LMAX) {
            out[(size_t)b * LMAX + l] = red[t] + red[128 + t] + red[256 + t] + red[384 + t];
        }
    }
}

// ---------------- Fallback (ws too small): straightforward f32 compute ----------------
__global__ __launch_bounds__(256)
void fallback_kernel(const float* __restrict__ attn, const float* __restrict__ sdelta,
                     const float* __restrict__ embt, const float* __restrict__ vw,
                     float* __restrict__ out) {
    const int idx = blockIdx.x * 256 + threadIdx.x;
    if (idx >= NB * LMAX) return;
    const int b = idx / LMAX;
    const int l = idx % LMAX;
    float s = 0.f;
    for (int m = 0; m < MLEN; ++m) {
        const float* ar = attn + ((size_t)b * MLEN + m) * EMBD;
        const float* er = embt + (size_t)(l + 1) * EMBD;
        float dot = 0.f;
        for (int e = 0; e < EMBD; ++e) dot += ar[e] * er[e];
        const size_t so = (((size_t)b * MLEN + m) * LMAX + l) * 2;
        s += dot * vw[m] * (sdelta[so] + sdelta[so + 1]);
    }
    out[idx] = s;
}

extern "C" void kernel_launch(void* const* d_in, const int* in_sizes, int n_in,
                              void* d_out, int out_size, void* d_ws, size_t ws_size,
                              hipStream_t stream) {
    const float* attn   = (const float*)d_in[0];  // [16][100][256] f32
    const float* sdelta = (const float*)d_in[1];  // [16][100][20000][2] f32
    // d_in[2] = traj_len — unused by the reference computation
    const float* embt   = (const float*)d_in[3];  // [20001][256] f32
    const float* vw     = (const float*)d_in[4];  // [1][100] f32
    float* out = (float*)d_out;                   // [16][20000] f32

    const size_t fragShorts = (size_t)PREP_TASKS * 8;            // 524288 u16 per array
    const size_t needed     = 2 * fragShorts * sizeof(unsigned short);  // 2 MB

    if (ws_size >= needed) {
        unsigned short* Bhi = (unsigned short*)d_ws;
        unsigned short* Blo = Bhi + fragShorts;
        prep2_kernel<<<PREP_TASKS / 256, 256, 0, stream>>>(attn, vw, Bhi, Blo);
        main_kernel<<<dim3(NB, NLT), 256, 0, stream>>>(Bhi, Blo, sdelta, embt, out);
    } else {
        fallback_kernel<<<(NB * LMAX + 255) / 256, 256, 0, stream>>>(attn, sdelta, embt, vw, out);
    }
}